// Round 1
// baseline (723.085 us; speedup 1.0000x reference)
//
#include <hip/hip_runtime.h>

#define N_NODES 100000
#define IN_DIM 256
#define OUT_DIM 64
#define GEMM_ROWS 32

// ---------------- degree histogram ----------------
__global__ __launch_bounds__(256) void deg_kernel(const int* __restrict__ src,
                                                  const int* __restrict__ dst,
                                                  float* __restrict__ deg_out,
                                                  float* __restrict__ deg_in, int E) {
    int i = blockIdx.x * blockDim.x + threadIdx.x;
    int stride = gridDim.x * blockDim.x;
    for (; i < E; i += stride) {
        atomicAdd(&deg_out[src[i]], 1.0f);
        atomicAdd(&deg_in[dst[i]], 1.0f);
    }
}

// ---------------- deg -> rsqrt(max(deg,1)) in place ----------------
__global__ __launch_bounds__(256) void norm_kernel(float* __restrict__ deg, int n) {
    int i = blockIdx.x * blockDim.x + threadIdx.x;
    if (i < n) {
        float d = deg[i];
        d = d < 1.0f ? 1.0f : d;
        deg[i] = rsqrtf(d);
    }
}

// ---------------- x = (h * norm_src[:,None]) @ W ----------------
// block = 256 threads, 32 rows per block (100000/32 = 3125 exact).
// h tile (32x256 fp32 = 32 KB) staged in LDS scaled by norm_src.
// thread (rg = tid>>6, j = tid&63) computes rows rg*8..rg*8+7, col j.
// Inner LDS reads are wave-uniform addresses -> broadcast, conflict-free.
__global__ __launch_bounds__(256) void gemm_kernel(const float* __restrict__ h,
                                                   const float* __restrict__ W,
                                                   const float* __restrict__ norm_src,
                                                   float* __restrict__ x) {
    __shared__ float hs[GEMM_ROWS * IN_DIM];
    const int row0 = blockIdx.x * GEMM_ROWS;
    const int t = threadIdx.x;

    // stage: 32*256 floats = 2048 float4, 8 per thread, coalesced
    const float4* hsrc = (const float4*)(h + (size_t)row0 * IN_DIM);
    float4* hdst = (float4*)hs;
#pragma unroll
    for (int it = 0; it < (GEMM_ROWS * IN_DIM / 4) / 256; ++it) {
        int f = t + it * 256;
        float4 v = hsrc[f];
        int row = (f * 4) / IN_DIM;
        float nrm = norm_src[row0 + row];
        v.x *= nrm; v.y *= nrm; v.z *= nrm; v.w *= nrm;
        hdst[f] = v;
    }
    __syncthreads();

    const int j = t & 63;
    const int rg = t >> 6;
    float acc[8] = {0.f, 0.f, 0.f, 0.f, 0.f, 0.f, 0.f, 0.f};

    for (int k = 0; k < IN_DIM; k += 4) {
        float w0 = W[(k + 0) * OUT_DIM + j];
        float w1 = W[(k + 1) * OUT_DIM + j];
        float w2 = W[(k + 2) * OUT_DIM + j];
        float w3 = W[(k + 3) * OUT_DIM + j];
#pragma unroll
        for (int r = 0; r < 8; ++r) {
            const float4 hv = *(const float4*)&hs[(rg * 8 + r) * IN_DIM + k];
            acc[r] = fmaf(hv.x, w0, acc[r]);
            acc[r] = fmaf(hv.y, w1, acc[r]);
            acc[r] = fmaf(hv.z, w2, acc[r]);
            acc[r] = fmaf(hv.w, w3, acc[r]);
        }
    }

#pragma unroll
    for (int r = 0; r < 8; ++r) {
        int row = row0 + rg * 8 + r;
        x[(size_t)row * OUT_DIM + j] = acc[r];
    }
}

// ---------------- edge scatter: one wave per edge ----------------
// lane j gathers x[src[e]][j], coalesced 256B atomic burst into out[dst[e]][j]
__global__ __launch_bounds__(256) void scatter_kernel(const int* __restrict__ src,
                                                      const int* __restrict__ dst,
                                                      const float* __restrict__ x,
                                                      float* __restrict__ out, int E) {
    const int lane = threadIdx.x & 63;
    const int wid = blockIdx.x * (blockDim.x >> 6) + (threadIdx.x >> 6);
    const int nwaves = gridDim.x * (blockDim.x >> 6);
    for (int e = wid; e < E; e += nwaves) {
        int s = src[e];
        int d = dst[e];
        float v = x[(size_t)s * OUT_DIM + lane];
        atomicAdd(&out[(size_t)d * OUT_DIM + lane], v);
    }
}

// ---------------- out = relu(out * norm_dst + b), in place ----------------
__global__ __launch_bounds__(256) void finalize_kernel(float* __restrict__ out,
                                                       const float* __restrict__ norm_dst,
                                                       const float* __restrict__ b) {
    int i = blockIdx.x * blockDim.x + threadIdx.x;  // float4 index
    const int total = N_NODES * OUT_DIM / 4;
    if (i >= total) return;
    float4 v = ((float4*)out)[i];
    int row = i >> 4;               // 16 float4 per row
    int col4 = (i & 15) * 4;
    float nrm = norm_dst[row];
    const float4 bv = *(const float4*)&b[col4];
    v.x = fmaxf(fmaf(v.x, nrm, bv.x), 0.f);
    v.y = fmaxf(fmaf(v.y, nrm, bv.y), 0.f);
    v.z = fmaxf(fmaf(v.z, nrm, bv.z), 0.f);
    v.w = fmaxf(fmaf(v.w, nrm, bv.w), 0.f);
    ((float4*)out)[i] = v;
}

extern "C" void kernel_launch(void* const* d_in, const int* in_sizes, int n_in,
                              void* d_out, int out_size, void* d_ws, size_t ws_size,
                              hipStream_t stream) {
    const float* h   = (const float*)d_in[0];
    const int*   src = (const int*)d_in[1];
    const int*   dst = (const int*)d_in[2];
    const float* W   = (const float*)d_in[3];
    const float* b   = (const float*)d_in[4];
    float* out = (float*)d_out;
    const int E = in_sizes[1];

    // workspace layout: [norm_src N][norm_dst N][x N*64]
    float* norms = (float*)d_ws;        // 2*N floats (deg then norm, in place)
    float* x     = norms + 2 * N_NODES; // 16B-aligned (800000 bytes offset)

    hipMemsetAsync(norms, 0, 2 * N_NODES * sizeof(float), stream);
    hipMemsetAsync(out, 0, (size_t)N_NODES * OUT_DIM * sizeof(float), stream);

    deg_kernel<<<2048, 256, 0, stream>>>(src, dst, norms, norms + N_NODES, E);
    norm_kernel<<<(2 * N_NODES + 255) / 256, 256, 0, stream>>>(norms, 2 * N_NODES);
    gemm_kernel<<<N_NODES / GEMM_ROWS, 256, 0, stream>>>(h, W, norms, x);
    scatter_kernel<<<8192, 256, 0, stream>>>(src, dst, x, out, E);
    finalize_kernel<<<(N_NODES * OUT_DIM / 4 + 255) / 256, 256, 0, stream>>>(out, norms + N_NODES, b);
}

// Round 2
// 520.582 us; speedup vs baseline: 1.3890x; 1.3890x over previous
//
#include <hip/hip_runtime.h>

#define N_NODES 100000
#define IN_DIM 256
#define OUT_DIM 64
#define GEMM_ROWS 32
#define SCAN_CHUNK 2048   // 256 threads * 8 elements
#define NSCAN_BLOCKS ((N_NODES + SCAN_CHUNK - 1) / SCAN_CHUNK)  // 49

// ---------------- degree histograms (int atomics, int4 edge loads) ----------------
__global__ __launch_bounds__(256) void deg_kernel(const int* __restrict__ src,
                                                  const int* __restrict__ dst,
                                                  int* __restrict__ deg_out,
                                                  int* __restrict__ deg_in, int E) {
    int i = blockIdx.x * blockDim.x + threadIdx.x;
    int stride = gridDim.x * blockDim.x;
    int n4 = E >> 2;
    const int4* src4 = (const int4*)src;
    const int4* dst4 = (const int4*)dst;
    for (int k = i; k < n4; k += stride) {
        int4 a = src4[k];
        atomicAdd(&deg_out[a.x], 1); atomicAdd(&deg_out[a.y], 1);
        atomicAdd(&deg_out[a.z], 1); atomicAdd(&deg_out[a.w], 1);
        int4 c = dst4[k];
        atomicAdd(&deg_in[c.x], 1); atomicAdd(&deg_in[c.y], 1);
        atomicAdd(&deg_in[c.z], 1); atomicAdd(&deg_in[c.w], 1);
    }
    // tail (E % 4)
    int t = n4 * 4 + i;
    if (t < E) { atomicAdd(&deg_out[src[t]], 1); atomicAdd(&deg_in[dst[t]], 1); }
}

// ---------------- per-block exclusive scan of deg_in ----------------
__global__ __launch_bounds__(256) void scan_blocks_kernel(const int* __restrict__ deg_in,
                                                          int* __restrict__ offs,
                                                          int* __restrict__ blocksums) {
    const int t = threadIdx.x;
    const int base = blockIdx.x * SCAN_CHUNK + t * 8;
    int pre[8];
    int s = 0;
#pragma unroll
    for (int r = 0; r < 8; ++r) {
        int v = (base + r < N_NODES) ? deg_in[base + r] : 0;
        pre[r] = s; s += v;
    }
    const int lane = t & 63;
    int incl = s;
#pragma unroll
    for (int off = 1; off < 64; off <<= 1) {
        int y = __shfl_up(incl, off);
        if (lane >= off) incl += y;
    }
    int wave_excl = incl - s;
    __shared__ int wtot[4];
    if (lane == 63) wtot[t >> 6] = incl;
    __syncthreads();
    int woff = 0;
    for (int w = 0; w < (t >> 6); ++w) woff += wtot[w];
    int bexcl = woff + wave_excl;
#pragma unroll
    for (int r = 0; r < 8; ++r)
        if (base + r < N_NODES) offs[base + r] = bexcl + pre[r];
    if (t == 0) blocksums[blockIdx.x] = wtot[0] + wtot[1] + wtot[2] + wtot[3];
}

// ---------------- scan the 49 block sums (single wave) ----------------
__global__ void scan_sums_kernel(int* __restrict__ blocksums) {
    int lane = threadIdx.x;
    int v = (lane < NSCAN_BLOCKS) ? blocksums[lane] : 0;
    int incl = v;
#pragma unroll
    for (int off = 1; off < 64; off <<= 1) {
        int y = __shfl_up(incl, off);
        if (lane >= off) incl += y;
    }
    if (lane < NSCAN_BLOCKS) blocksums[lane] = incl - v;
}

// ---------------- add block offsets; init cursors; compute norms ----------------
__global__ __launch_bounds__(256) void add_norm_kernel(int* __restrict__ offs, int* __restrict__ cur,
                                                       const int* __restrict__ deg_out,
                                                       const int* __restrict__ deg_in,
                                                       const int* __restrict__ blocksums,
                                                       float* __restrict__ norm_src,
                                                       float* __restrict__ norm_dst) {
    int i = blockIdx.x * blockDim.x + threadIdx.x;
    if (i >= N_NODES) return;
    int o = offs[i] + blocksums[i / SCAN_CHUNK];
    offs[i] = o;
    cur[i] = o;
    int dout = deg_out[i]; if (dout < 1) dout = 1;
    int din  = deg_in[i];  if (din  < 1) din  = 1;
    norm_src[i] = rsqrtf((float)dout);
    norm_dst[i] = rsqrtf((float)din);
}

// ---------------- CSR fill: csr_src[cur[dst]++] = src ----------------
__global__ __launch_bounds__(256) void fill_kernel(const int* __restrict__ src,
                                                   const int* __restrict__ dst,
                                                   int* __restrict__ cur,
                                                   int* __restrict__ csr_src, int E) {
    int i = blockIdx.x * blockDim.x + threadIdx.x;
    int stride = gridDim.x * blockDim.x;
    int n4 = E >> 2;
    const int4* src4 = (const int4*)src;
    const int4* dst4 = (const int4*)dst;
    for (int k = i; k < n4; k += stride) {
        int4 a = src4[k];
        int4 c = dst4[k];
        csr_src[atomicAdd(&cur[c.x], 1)] = a.x;
        csr_src[atomicAdd(&cur[c.y], 1)] = a.y;
        csr_src[atomicAdd(&cur[c.z], 1)] = a.z;
        csr_src[atomicAdd(&cur[c.w], 1)] = a.w;
    }
    int t = n4 * 4 + i;
    if (t < E) csr_src[atomicAdd(&cur[dst[t]], 1)] = src[t];
}

// ---------------- x = (h * norm_src[:,None]) @ W ----------------
__global__ __launch_bounds__(256) void gemm_kernel(const float* __restrict__ h,
                                                   const float* __restrict__ W,
                                                   const float* __restrict__ norm_src,
                                                   float* __restrict__ x) {
    __shared__ float hs[GEMM_ROWS * IN_DIM];
    const int row0 = blockIdx.x * GEMM_ROWS;
    const int t = threadIdx.x;

    const float4* hsrc = (const float4*)(h + (size_t)row0 * IN_DIM);
    float4* hdst = (float4*)hs;
#pragma unroll
    for (int it = 0; it < (GEMM_ROWS * IN_DIM / 4) / 256; ++it) {
        int f = t + it * 256;
        float4 v = hsrc[f];
        int row = (f * 4) / IN_DIM;
        float nrm = norm_src[row0 + row];
        v.x *= nrm; v.y *= nrm; v.z *= nrm; v.w *= nrm;
        hdst[f] = v;
    }
    __syncthreads();

    const int j = t & 63;
    const int rg = t >> 6;
    float acc[8] = {0.f, 0.f, 0.f, 0.f, 0.f, 0.f, 0.f, 0.f};

    for (int k = 0; k < IN_DIM; k += 4) {
        float w0 = W[(k + 0) * OUT_DIM + j];
        float w1 = W[(k + 1) * OUT_DIM + j];
        float w2 = W[(k + 2) * OUT_DIM + j];
        float w3 = W[(k + 3) * OUT_DIM + j];
#pragma unroll
        for (int r = 0; r < 8; ++r) {
            const float4 hv = *(const float4*)&hs[(rg * 8 + r) * IN_DIM + k];
            acc[r] = fmaf(hv.x, w0, acc[r]);
            acc[r] = fmaf(hv.y, w1, acc[r]);
            acc[r] = fmaf(hv.z, w2, acc[r]);
            acc[r] = fmaf(hv.w, w3, acc[r]);
        }
    }

#pragma unroll
    for (int r = 0; r < 8; ++r) {
        int row = row0 + rg * 8 + r;
        x[(size_t)row * OUT_DIM + j] = acc[r];
    }
}

// ---------------- aggregate: one wave per node, gather-sum, fused epilogue ----------------
__global__ __launch_bounds__(256) void aggregate_kernel(const int* __restrict__ offs,
                                                        const int* __restrict__ cur,
                                                        const int* __restrict__ csr_src,
                                                        const float* __restrict__ x,
                                                        const float* __restrict__ norm_dst,
                                                        const float* __restrict__ b,
                                                        float* __restrict__ out) {
    const int lane = threadIdx.x & 63;
    const int node = blockIdx.x * 4 + (threadIdx.x >> 6);
    if (node >= N_NODES) return;
    const int start = offs[node];
    const int cnt = cur[node] - start;

    float acc = 0.f;
    for (int base = 0; base < cnt; base += 64) {
        int k = base + lane;
        int sidx = (k < cnt) ? csr_src[start + k] : 0;   // lane-parallel index batch
        int m = cnt - base; if (m > 64) m = 64;
        int t = 0;
        for (; t + 4 <= m; t += 4) {                      // 4 loads in flight
            int s0 = __shfl(sidx, t);
            int s1 = __shfl(sidx, t + 1);
            int s2 = __shfl(sidx, t + 2);
            int s3 = __shfl(sidx, t + 3);
            float v0 = x[(size_t)s0 * OUT_DIM + lane];
            float v1 = x[(size_t)s1 * OUT_DIM + lane];
            float v2 = x[(size_t)s2 * OUT_DIM + lane];
            float v3 = x[(size_t)s3 * OUT_DIM + lane];
            acc += (v0 + v1) + (v2 + v3);
        }
        for (; t < m; ++t) {
            int s = __shfl(sidx, t);
            acc += x[(size_t)s * OUT_DIM + lane];
        }
    }
    float r = fmaf(acc, norm_dst[node], b[lane]);
    out[(size_t)node * OUT_DIM + lane] = r > 0.f ? r : 0.f;
}

extern "C" void kernel_launch(void* const* d_in, const int* in_sizes, int n_in,
                              void* d_out, int out_size, void* d_ws, size_t ws_size,
                              hipStream_t stream) {
    const float* h   = (const float*)d_in[0];
    const int*   src = (const int*)d_in[1];
    const int*   dst = (const int*)d_in[2];
    const float* W   = (const float*)d_in[3];
    const float* b   = (const float*)d_in[4];
    float* out = (float*)d_out;
    const int E = in_sizes[1];

    // workspace layout (all 16B aligned):
    char* ws = (char*)d_ws;
    int*   deg_out   = (int*)(ws);                           // N ints
    int*   deg_in    = (int*)(ws + 400000);                  // N ints
    float* norm_src  = (float*)(ws + 800000);                // N floats
    float* norm_dst  = (float*)(ws + 1200000);               // N floats
    int*   offs      = (int*)(ws + 1600000);                 // N ints
    int*   cur       = (int*)(ws + 2000000);                 // N ints
    int*   blocksums = (int*)(ws + 2400000);                 // 64 ints
    int*   csr_src   = (int*)(ws + 2400256);                 // E ints (6.4 MB)
    float* x         = (float*)(ws + 8800256);               // N*64 floats (25.6 MB)

    hipMemsetAsync(deg_out, 0, 2 * N_NODES * sizeof(int), stream);  // deg_out + deg_in

    deg_kernel<<<1024, 256, 0, stream>>>(src, dst, deg_out, deg_in, E);
    scan_blocks_kernel<<<NSCAN_BLOCKS, 256, 0, stream>>>(deg_in, offs, blocksums);
    scan_sums_kernel<<<1, 64, 0, stream>>>(blocksums);
    add_norm_kernel<<<(N_NODES + 255) / 256, 256, 0, stream>>>(offs, cur, deg_out, deg_in,
                                                               blocksums, norm_src, norm_dst);
    fill_kernel<<<1024, 256, 0, stream>>>(src, dst, cur, csr_src, E);
    gemm_kernel<<<N_NODES / GEMM_ROWS, 256, 0, stream>>>(h, W, norm_src, x);
    aggregate_kernel<<<(N_NODES + 3) / 4, 256, 0, stream>>>(offs, cur, csr_src, x,
                                                            norm_dst, b, out);
}